// Round 1
// baseline (319.889 us; speedup 1.0000x reference)
//
#include <hip/hip_runtime.h>

// Problem constants (from reference):
//   x: (160,128,48,48) f32, vth: (160,3) f32, mask_rand: (160,48,48) f32
//   TIME_STEP=5, bs=32, TAU=0.5, A=1.0 (step threshold at 0), LAYER=1 -> vth[:,0]
//   DropBlock: gamma = 0.2/49, 7x7 stride-1 SAME max-pool, bm = 1 - pooled
constexpr int N_   = 160;
constexpr int C_   = 128;
constexpr int H_   = 48;
constexpr int W_   = 48;
constexpr int T_   = 5;
constexpr int BS_  = 32;              // batch per time step
constexpr int HW_  = H_ * W_;         // 2304
constexpr int HW4_ = HW_ / 4;         // 576 (float4 units) = exactly 9 waves
constexpr int CHW_ = C_ * HW_;        // 294912

typedef float f32x4 __attribute__((ext_vector_type(4)));

// Kernel 1: DropBlock mask, separable max-pool, one block per (n, 8-row strip).
// 960 blocks for CU coverage; 7+7 ops/output instead of 49.
constexpr int STRIP_ROWS = 8;
constexpr int STRIPS     = H_ / STRIP_ROWS;  // 6
constexpr int HALO_ROWS  = STRIP_ROWS + 6;   // 14 (3-row halo each side)

__global__ __launch_bounds__(256) void block_mask_k(const float* __restrict__ mr,
                                                    float* __restrict__ bm) {
    const int n  = blockIdx.x / STRIPS;
    const int s  = blockIdx.x % STRIPS;
    const int r0 = s * STRIP_ROWS;
    constexpr float GAMMA = 0.2f / 49.0f;

    __shared__ float seed[HALO_ROWS][W_];   // binarized seeds (OOB rows -> 0)
    __shared__ float hmax[HALO_ROWS][W_];   // 7-wide horizontal max

    const float* src = mr + (size_t)n * HW_;

    // Stage A: load + binarize seeds for rows [r0-3, r0+10], clip to 0 outside
    for (int i = threadIdx.x; i < HALO_ROWS * W_; i += 256) {
        const int lr = i / W_, w = i % W_;
        const int gr = r0 - 3 + lr;
        float v = 0.0f;
        if (gr >= 0 && gr < H_) v = (src[gr * W_ + w] < GAMMA) ? 1.0f : 0.0f;
        seed[lr][w] = v;
    }
    __syncthreads();

    // Stage B: horizontal 7-window max (OOB columns contribute 0 == clamped max)
    for (int i = threadIdx.x; i < HALO_ROWS * W_; i += 256) {
        const int lr = i / W_, w = i % W_;
        float m = 0.0f;
#pragma unroll
        for (int dw = -3; dw <= 3; ++dw) {
            const int ww = w + dw;
            if (ww >= 0 && ww < W_) m = fmaxf(m, seed[lr][ww]);
        }
        hmax[lr][w] = m;
    }
    __syncthreads();

    // Stage C: vertical 7-window max, write bm rows [r0, r0+8)
    float* dst = bm + (size_t)n * HW_;
    for (int i = threadIdx.x; i < STRIP_ROWS * W_; i += 256) {
        const int lh = i / W_, w = i % W_;
        float m = 0.0f;
#pragma unroll
        for (int dr = 0; dr < 7; ++dr)
            m = fmaxf(m, hmax[lh + dr][w]);
        dst[(r0 + lh) * W_ + w] = 1.0f - m;
    }
}

// Kernel 2: LIF recurrence. Thread owns (b, channel-group-of-CPT, hw4 f32x4).
// vth (5 scalars) + bm (5 x f32x4) loaded ONCE per thread, reused across CPT
// channels -> 5x fewer bm VMEM issues vs per-(b,c) mapping. x/out streamed
// nontemporal, 1 KB/wave coalesced. u-state lives in registers per channel.
// u_new = (u_old >= v ? 0 : 0.5*u_old) + x_t ;  out_t = (u_new >= v) ? bm_t : 0
constexpr int CPT = 8;            // channels per thread
constexpr int CG_ = C_ / CPT;     // 16 channel groups

__global__ __launch_bounds__(256) void lif_k(const float* __restrict__ x,
                                             const float* __restrict__ vth,
                                             const float* __restrict__ bm,
                                             float* __restrict__ out) {
    const int tid = blockIdx.x * blockDim.x + threadIdx.x;  // 294,912 total
    const int hw4 = tid % HW4_;       // waves never straddle (b,cg): 576 = 9*64
    const int rem = tid / HW4_;
    const int cg  = rem % CG_;
    const int b   = rem / CG_;

    constexpr size_t T_STRIDE = (size_t)BS_ * CHW_;   // elements between steps

    // Preload per-(b,hw4) time-step constants: reused across all CPT channels.
    float v[T_];
    f32x4 bt[T_];
#pragma unroll
    for (int t = 0; t < T_; ++t) {
        const int n = t * BS_ + b;
        v[t]  = vth[(size_t)n * 3];   // LAYER-1 == 0; wave-uniform
        bt[t] = reinterpret_cast<const f32x4*>(bm + (size_t)n * HW_)[hw4];
    }

    const size_t base0 = (size_t)b * CHW_ + (size_t)(cg * CPT) * HW_ + (size_t)hw4 * 4;

#pragma unroll 1   // keep VGPRs bounded; t-loop below is fully unrolled
    for (int ci = 0; ci < CPT; ++ci) {
        const size_t base = base0 + (size_t)ci * HW_;
        float ux = 0.0f, uy = 0.0f, uz = 0.0f, uw = 0.0f;
#pragma unroll
        for (int t = 0; t < T_; ++t) {
            const f32x4 xt = __builtin_nontemporal_load(
                reinterpret_cast<const f32x4*>(x + base + (size_t)t * T_STRIDE));

            ux = (ux >= v[t] ? 0.0f : 0.5f * ux) + xt.x;
            uy = (uy >= v[t] ? 0.0f : 0.5f * uy) + xt.y;
            uz = (uz >= v[t] ? 0.0f : 0.5f * uz) + xt.z;
            uw = (uw >= v[t] ? 0.0f : 0.5f * uw) + xt.w;

            f32x4 o;
            o.x = (ux >= v[t]) ? bt[t].x : 0.0f;
            o.y = (uy >= v[t]) ? bt[t].y : 0.0f;
            o.z = (uz >= v[t]) ? bt[t].z : 0.0f;
            o.w = (uw >= v[t]) ? bt[t].w : 0.0f;
            __builtin_nontemporal_store(
                o, reinterpret_cast<f32x4*>(out + base + (size_t)t * T_STRIDE));
        }
    }
}

extern "C" void kernel_launch(void* const* d_in, const int* in_sizes, int n_in,
                              void* d_out, int out_size, void* d_ws, size_t ws_size,
                              hipStream_t stream) {
    const float* x    = (const float*)d_in[0];
    const float* vth  = (const float*)d_in[1];
    const float* mr   = (const float*)d_in[2];
    float* out = (float*)d_out;
    float* bm  = (float*)d_ws;  // N_*HW_ floats = 1.47 MB scratch

    block_mask_k<<<N_ * STRIPS, 256, 0, stream>>>(mr, bm);

    const int total_threads = BS_ * CG_ * HW4_;  // 294,912
    const int block = 256;
    const int grid = total_threads / block;      // 1152, exact
    lif_k<<<grid, block, 0, stream>>>(x, vth, bm, out);
}